// Round 1
// baseline (1136.343 us; speedup 1.0000x reference)
//
#include <hip/hip_runtime.h>
#include <hip/hip_fp16.h>
#include <math.h>

// Problem constants
#define DM    1024
#define FFD   4096
#define VOCAB 32000
#define NCAT  75
#define UNK_IDX 1
#define EPS   1e-5f
#define NB    8
#define SEQ   2048
#define T_TOK (NB*SEQ)   // 16384 tokens

using u16   = unsigned short;
using half_t = _Float16;
using half8 = __attribute__((ext_vector_type(8))) _Float16;  // MFMA A/B frag (4 VGPRs)
using f32x4 = __attribute__((ext_vector_type(4))) float;     // MFMA C/D frag

struct alignas(8) h4 { half_t s[4]; };

// async global->LDS, 16 B per lane; LDS dest = wave-uniform base + lane*16
__device__ __forceinline__ void async16(const half_t* g, half_t* l) {
    __builtin_amdgcn_global_load_lds(
        (const __attribute__((address_space(1))) void*)g,
        (__attribute__((address_space(3))) void*)l,
        16, 0, 0);
}

// ---------------------------------------------------------------------------
// Positional-encoding table [SEQ][DM] fp32 (computed once, shared by batch)
// ---------------------------------------------------------------------------
__global__ __launch_bounds__(256)
void pe_kernel(float* __restrict__ pe)
{
    int gid = blockIdx.x * blockDim.x + threadIdx.x;   // over SEQ*DM
    if (gid >= SEQ * DM) return;
    int dcol = gid & (DM - 1);
    int t    = gid >> 10;
    int p = dcol >> 1;
    float power = (float)p / 512.0f;
    float denom = powf(10000.0f, power);
    float ang = (float)t / denom;
    pe[gid] = (dcol & 1) ? cosf(ang) : sinf(ang);
}

// ---------------------------------------------------------------------------
// Embedding gather + PE add -> Xf (fp32) and Xh (fp16), float4-vectorized
// ---------------------------------------------------------------------------
__global__ __launch_bounds__(256)
void embed_pos_kernel(const int* __restrict__ idx,
                      const float* __restrict__ emb,
                      const float* __restrict__ pe,
                      float* __restrict__ xf, half_t* __restrict__ xh)
{
    int gid4 = blockIdx.x * blockDim.x + threadIdx.x;  // over T_TOK*DM/4
    if (gid4 >= T_TOK * DM / 4) return;
    int tok = gid4 >> 8;            // DM/4 = 256 float4 per token
    int c4  = (gid4 & 255) << 2;
    int t   = tok & (SEQ - 1);
    int id = idx[tok];
    if (id >= VOCAB || id < 0) id = UNK_IDX;
    float4 e = *(const float4*)(emb + (long long)id * DM + c4);
    float4 q = *(const float4*)(pe + (long long)t * DM + c4);
    float4 v = make_float4(e.x + q.x, e.y + q.y, e.z + q.z, e.w + q.w);
    *(float4*)(xf + (long long)tok * DM + c4) = v;
    h4 pk = {{(half_t)v.x, (half_t)v.y, (half_t)v.z, (half_t)v.w}};
    *(h4*)(xh + (long long)tok * DM + c4) = pk;
}

// ---------------------------------------------------------------------------
// Weight transpose + fp32->fp16: in [K,N] fp32 -> out [Npad,K] fp16
// ---------------------------------------------------------------------------
__global__ __launch_bounds__(256)
void transpose_h_kernel(const float* __restrict__ in, half_t* __restrict__ out,
                        int K, int N, int Npad)
{
    __shared__ float t[32][33];
    int n0 = blockIdx.x * 32, k0 = blockIdx.y * 32;
    int tx = threadIdx.x & 31, ty = threadIdx.x >> 5;   // ty 0..7
#pragma unroll
    for (int i = 0; i < 4; i++) {
        int k = k0 + ty + i * 8, n = n0 + tx;
        t[ty + i * 8][tx] = (k < K && n < N) ? in[(long long)k * N + n] : 0.f;
    }
    __syncthreads();
#pragma unroll
    for (int i = 0; i < 4; i++) {
        int n = n0 + ty + i * 8, k = k0 + tx;
        if (n < Npad && k < K)
            out[(long long)n * K + k] = (half_t)t[tx][ty + i * 8];
    }
}

// pad b4 [75] -> b4p [128]
__global__ __launch_bounds__(128)
void pad_bias_kernel(const float* __restrict__ b, float* __restrict__ bp)
{
    int i = threadIdx.x;
    bp[i] = (i < NCAT) ? b[i] : 0.f;
}

// ---------------------------------------------------------------------------
// fp16 MFMA NT GEMM, software-pipelined dbuf K-loop (m97 shape) + LDS-staged
// coalesced epilogue.
//   C = scale*(A @ B^T) + bias [+ resid] [,relu]; fp16 in, fp32 acc.
//   128x128 tile, BK=32, 256 thr = 4 waves (2x2), 4x4 16x16x32 MFMA/wave.
//   K-loop LDS: 2 tensors x 2 buffers x 8 KB = 32 KB (XOR chunk swizzle).
//   Epilogue: same 32 KB re-staged as fp32 [32][132] chunks -> float4 stores.
// blockIdx.z decode: kz = z & ((1<<ksh)-1) selects a K-split (A += kz*sKA,
//   B += kz*sKB, C += kz*sKC for OUT_MODE 0); zb = z >> ksh is the batch
//   (A += zb*sA etc). Split-K callers pass bias=nullptr (bias applied once
//   downstream) and resid=nullptr.
// XCD swizzle: bijective m204 chunk remap of the xy tile plane so blocks
//   sharing A row-panels / B col-panels land on the same XCD L2.
// OUT_MODE: 0 = fp32 [M,N] at C + zb*sC + kz*sKC (+resid); 1 = fp16 [M,N];
//           2 = fp16 KV-transposed [b][n][t], b=row>>11, t=row&2047.
// ---------------------------------------------------------------------------
template<int OUT_MODE>
__global__ __launch_bounds__(256)
void gemm_nt(const half_t* __restrict__ A, const half_t* __restrict__ B,
             const float* __restrict__ bias, const float* __restrict__ resid,
             void* __restrict__ Cout,
             int M, int N, int K, int ld,
             long long sA, long long sB, long long sC,
             long long sKA, long long sKB, long long sKC, int ksh,
             float scale, int do_relu)
{
    const int kz = (int)(blockIdx.z & ((1u << ksh) - 1u));
    const int zb = (int)(blockIdx.z >> ksh);
    A += (long long)zb * sA + (long long)kz * sKA;
    B += (long long)zb * sB + (long long)kz * sKB;

    // XCD-bijective chunked swizzle (m204): consecutive dispatch ids round-
    // robin over 8 XCDs; remap so each XCD owns a contiguous tile range.
    const int nxy  = gridDim.x * gridDim.y;
    const int orig = blockIdx.y * gridDim.x + blockIdx.x;
    const int q = nxy >> 3, r = nxy & 7;
    const int xcd = orig & 7, loc = orig >> 3;
    const int wg  = (xcd < r ? xcd * (q + 1) : r * (q + 1) + (xcd - r) * q) + loc;
    const int bx  = wg % gridDim.x;
    const int by  = wg / gridDim.x;

    const int tid  = threadIdx.x;
    const int lane = tid & 63;
    const int w    = tid >> 6;          // wave 0..3
    const int wm   = w >> 1, wn = w & 1;
    const long long row0 = (long long)by * 128;
    const long long col0 = (long long)bx * 128;

    __shared__ half_t smem[4 * 4096];   // 2 tensors x 2 buffers x 8 KB
    half_t* const As = smem;
    half_t* const Bs = smem + 2 * 4096;

    f32x4 acc[4][4];
    const f32x4 zero = {0.f, 0.f, 0.f, 0.f};
#pragma unroll
    for (int i = 0; i < 4; i++)
#pragma unroll
        for (int j = 0; j < 4; j++) acc[i][j] = zero;

    const int ldrow = lane >> 2;                                  // staging row in 16-row chunk
    const int swcol = (((lane & 3) << 3)) ^ ((ldrow & 3) << 3);   // swizzled source col
    const int fr    = lane & 15;                                  // fragment row
    const int kk8   = (lane >> 4) << 3;                           // fragment k offset

    const int KT = K / 32;

#define ISSUE(k0, buf)                                                         \
    {                                                                          \
        _Pragma("unroll")                                                      \
        for (int it = 0; it < 2; ++it) {                                       \
            int rb = (it * 4 + w) * 16;                                        \
            long long ao = (row0 + rb + ldrow) * (long long)ld + (k0) + swcol; \
            long long bo = (col0 + rb + ldrow) * (long long)ld + (k0) + swcol; \
            async16(A + ao, As + (buf) * 4096 + rb * 32);                      \
            async16(B + bo, Bs + (buf) * 4096 + rb * 32);                      \
        }                                                                      \
    }

    ISSUE(0, 0);
    for (int kt = 0; kt < KT; ++kt) {
        const int cur = kt & 1;
        __syncthreads();                 // cur buffer ready; prev consumers done
        if (kt + 1 < KT) ISSUE((kt + 1) * 32, cur ^ 1);

        half8 af[4], bf[4];
#pragma unroll
        for (int i = 0; i < 4; ++i) {
            int r   = wm * 64 + i * 16 + fr;
            int off = cur * 4096 + r * 32 + (kk8 ^ ((r & 3) << 3));
            af[i] = *(const half8*)(As + off);
        }
#pragma unroll
        for (int j = 0; j < 4; ++j) {
            int r   = wn * 64 + j * 16 + fr;
            int off = cur * 4096 + r * 32 + (kk8 ^ ((r & 3) << 3));
            bf[j] = *(const half8*)(Bs + off);
        }
#pragma unroll
        for (int i = 0; i < 4; ++i)
#pragma unroll
            for (int j = 0; j < 4; ++j)
                acc[i][j] = __builtin_amdgcn_mfma_f32_16x16x32_f16(
                    af[i], bf[j], acc[i][j], 0, 0, 0);
    }
#undef ISSUE

    // ---- LDS-staged epilogue ------------------------------------------------
    // C/D layout: col = lane&15, row = (lane>>4)*4 + reg. Stage 4 chunks of
    // 32 rows (wm=0: i*16+0..15, wm=1: 64+i*16+0..15) x 128 cols into fp32
    // LDS [32][132], then emit float4-coalesced global traffic.
    float* ls = (float*)smem;           // 32*132*4 = 16.9 KB <= 32 KB
    const int ldp = 132;
    const int qr = (lane >> 4) * 4;
    const int lc = lane & 15;
    float bvj[4];
#pragma unroll
    for (int j = 0; j < 4; ++j)
        bvj[j] = bias ? bias[col0 + wn * 64 + j * 16 + lc] : 0.f;
    const float* rz = (OUT_MODE == 0 && resid) ? resid + (long long)zb * sC : nullptr;

#pragma unroll
    for (int i = 0; i < 4; ++i) {
        __syncthreads();                // LDS free (K-loop or previous chunk done)
#pragma unroll
        for (int j = 0; j < 4; ++j) {
            int col = wn * 64 + j * 16 + lc;
#pragma unroll
            for (int r = 0; r < 4; ++r) {
                float f = acc[i][j][r] * scale + bvj[j];
                if (do_relu) f = fmaxf(f, 0.f);
                ls[(wm * 16 + qr + r) * ldp + col] = f;
            }
        }
        __syncthreads();
        if (OUT_MODE == 2) {
            // write along t: idx -> n = idx>>3 (0..127), k = idx&7; rows lr=4k..4k+3
#pragma unroll
            for (int rep = 0; rep < 4; ++rep) {
                int idx = rep * 256 + tid;      // 0..1023
                int n   = idx >> 3;
                int k   = idx & 7;
                int lr0 = k * 4;
                h4 pk;
                long long arow0 = (lr0 < 16 ? 0 : 48) + i * 16 + lr0;
#pragma unroll
                for (int r = 0; r < 4; ++r)
                    pk.s[r] = (half_t)ls[(lr0 + r) * ldp + n];
                long long gr = row0 + arow0;    // 4 consecutive tokens
                int b  = (int)(gr >> 11);
                int tl = (int)(gr & (SEQ - 1));
                half_t* C = (half_t*)Cout;
                *(h4*)(C + (long long)b * N * SEQ + (col0 + n) * SEQ + tl) = pk;
            }
        } else {
#pragma unroll
            for (int rep = 0; rep < 4; ++rep) {
                int idx = rep * 256 + tid;      // 0..1023
                int lr  = idx >> 5;             // 0..31
                int c4  = (idx & 31) << 2;      // col offset 0..124
                long long arow = (lr < 16 ? 0 : 48) + i * 16 + lr;
                float4 v = *(float4*)&ls[lr * ldp + c4];
                long long base = (row0 + arow) * N + col0 + c4;
                if (OUT_MODE == 0) {
                    float* C = (float*)Cout + (long long)zb * sC + (long long)kz * sKC;
                    if (rz) {
                        float4 x = *(const float4*)(rz + base);
                        v.x += x.x; v.y += x.y; v.z += x.z; v.w += x.w;
                    }
                    *(float4*)(C + base) = v;
                } else {
                    half_t* C = (half_t*)Cout + (long long)zb * sC;
                    h4 pk = {{(half_t)v.x, (half_t)v.y, (half_t)v.z, (half_t)v.w}};
                    *(h4*)(C + base) = pk;
                }
            }
        }
    }
}

// ---------------------------------------------------------------------------
// LN(X [+ Y] [+ Z] [+ cb]) * g + b over DM=1024, float4-vectorized, one
// block/row. cb is a per-column [DM] bias (e.g. b2 folded out of a split-K
// GEMM). In-place safe (outf may alias X): all reads precede writes.
// ---------------------------------------------------------------------------
__global__ __launch_bounds__(256)
void add_ln_kernel(const float* __restrict__ X, const float* __restrict__ Y,
                   const float* __restrict__ Z, const float* __restrict__ cb,
                   const float* __restrict__ g, const float* __restrict__ b,
                   float* __restrict__ outf, half_t* __restrict__ outh)
{
    int row = blockIdx.x;
    int tid = threadIdx.x;
    float4 v = ((const float4*)(X + (long long)row * DM))[tid];
    if (Y) {
        float4 y = ((const float4*)(Y + (long long)row * DM))[tid];
        v.x += y.x; v.y += y.y; v.z += y.z; v.w += y.w;
    }
    if (Z) {
        float4 z = ((const float4*)(Z + (long long)row * DM))[tid];
        v.x += z.x; v.y += z.y; v.z += z.z; v.w += z.w;
    }
    if (cb) {
        float4 c = ((const float4*)cb)[tid];
        v.x += c.x; v.y += c.y; v.z += c.z; v.w += c.w;
    }
    float s  = v.x + v.y + v.z + v.w;
    float s2 = v.x * v.x + v.y * v.y + v.z * v.z + v.w * v.w;
#pragma unroll
    for (int o = 1; o < 64; o <<= 1) {
        s  += __shfl_xor(s,  o, 64);
        s2 += __shfl_xor(s2, o, 64);
    }
    __shared__ float rs[4], rs2[4], stats[2];
    int wid = tid >> 6;
    if ((tid & 63) == 0) { rs[wid] = s; rs2[wid] = s2; }
    __syncthreads();
    if (tid == 0) {
        float S  = rs[0] + rs[1] + rs[2] + rs[3];
        float S2 = rs2[0] + rs2[1] + rs2[2] + rs2[3];
        float mean = S / (float)DM;
        float var  = S2 / (float)DM - mean * mean;   // biased var == jnp.var
        stats[0] = mean;
        stats[1] = rsqrtf(var + EPS);
    }
    __syncthreads();
    float mean = stats[0], rstd = stats[1];
    float4 gg = ((const float4*)g)[tid];
    float4 bb = ((const float4*)b)[tid];
    float4 o;
    o.x = (v.x - mean) * rstd * gg.x + bb.x;
    o.y = (v.y - mean) * rstd * gg.y + bb.y;
    o.z = (v.z - mean) * rstd * gg.z + bb.z;
    o.w = (v.w - mean) * rstd * gg.w + bb.w;
    if (outf) ((float4*)(outf + (long long)row * DM))[tid] = o;
    h4 pk = {{(half_t)o.x, (half_t)o.y, (half_t)o.z, (half_t)o.w}};
    *(h4*)(outh + (long long)row * DM + tid * 4) = pk;
}

// ---------------------------------------------------------------------------
// out[row,:] = sigmoid(LN75(L[row,0:75]) * g + b); L leading dim 128
// ---------------------------------------------------------------------------
__global__ __launch_bounds__(64)
void ln75_sigmoid_kernel(const float* __restrict__ L,
                         const float* __restrict__ g, const float* __restrict__ b,
                         float* __restrict__ out)
{
    int row = blockIdx.x;
    int t   = threadIdx.x;
    const float* lr = L + (long long)row * 128;
    float e0 = (t < NCAT) ? lr[t] : 0.f;
    float e1 = (t + 64 < NCAT) ? lr[t + 64] : 0.f;
    float s  = e0 + e1;
    float s2 = e0 * e0 + e1 * e1;
#pragma unroll
    for (int o = 1; o < 64; o <<= 1) {
        s  += __shfl_xor(s,  o, 64);
        s2 += __shfl_xor(s2, o, 64);
    }
    float mean = s / (float)NCAT;
    float var  = s2 / (float)NCAT - mean * mean;
    float rstd = rsqrtf(var + EPS);
    if (t < NCAT) {
        float z = (e0 - mean) * rstd * g[t] + b[t];
        out[(long long)row * NCAT + t] = 1.f / (1.f + expf(-z));
    }
    if (t + 64 < NCAT) {
        float z = (e1 - mean) * rstd * g[t + 64] + b[t + 64];
        out[(long long)row * NCAT + t + 64] = 1.f / (1.f + expf(-z));
    }
}

// ---------------------------------------------------------------------------
// Orchestration. Attention fully folded:
//   (QK^T/8)V Wu + bu + x == Q @ M2t^T + bu + x,
//   ktv2[b][k][v] = 0.125 * sum_t K[t,k]V[t,v]  = NT(Kt, Vt) * 0.125
//   M2t[b][n][k]  = sum_v Wu[v,n] ktv2[k][v]    = NT(Wuh, ktv2[b])
//   usum          = NT(Q, M2t[b]) + bu + Xf     (fp32, residual fused)
// FFN2 is split-K=2 (grid z): partials land in the dead Xf region (R_A) and
// the partial-sum + b2 bias is fused into the second LayerNorm (per chunk).
// ---------------------------------------------------------------------------
extern "C" void kernel_launch(void* const* d_in, const int* in_sizes, int n_in,
                              void* d_out, int out_size, void* d_ws, size_t ws_size,
                              hipStream_t stream)
{
    const int*   idx = (const int*)  d_in[0];
    const float* emb = (const float*)d_in[1];
    const float* Wq  = (const float*)d_in[2];
    const float* bq  = (const float*)d_in[3];
    const float* Wk  = (const float*)d_in[4];
    const float* bk  = (const float*)d_in[5];
    const float* Wv  = (const float*)d_in[6];
    const float* bv  = (const float*)d_in[7];
    const float* Wu  = (const float*)d_in[8];
    const float* bu  = (const float*)d_in[9];
    const float* g1  = (const float*)d_in[10];
    const float* be1 = (const float*)d_in[11];
    const float* W1  = (const float*)d_in[12];
    const float* b1  = (const float*)d_in[13];
    const float* W2  = (const float*)d_in[14];
    const float* b2  = (const float*)d_in[15];
    const float* g2  = (const float*)d_in[16];
    const float* be2 = (const float*)d_in[17];
    const float* W3  = (const float*)d_in[18];
    const float* b3  = (const float*)d_in[19];
    const float* W4  = (const float*)d_in[20];
    const float* b4  = (const float*)d_in[21];
    const float* g3  = (const float*)d_in[22];
    const float* be3 = (const float*)d_in[23];

    const long long TD  = (long long)T_TOK * DM;       // 16.78M
    char* p = (char*)d_ws;
    char* R_A = p; p += TD * 4;
    char* R_B = p; p += TD * 2;
    char* R_C = p; p += TD * 2;
    char* R_D = p; p += TD * 2;                        // 32 MB (Kt) ...
    char* R_D2 = p; p += TD * 2;                       // 32 MB (Vt); R_D..R_D2 = 64MB f1h
    char* R_E = p; p += TD * 4;
    char* R_F = p; p += (long long)NB * DM * DM * 4;   // 32 MB
    char* R_G = p; p += (long long)T_TOK * 128 * 4;    // 8 MB
    float* pe = (float*)p; p += (long long)SEQ * DM * 4; // 8 MB
    half_t* Wqh = (half_t*)p; p += DM*DM*2;
    half_t* Wkh = (half_t*)p; p += DM*DM*2;
    half_t* Wvh = (half_t*)p; p += DM*DM*2;
    half_t* Wuh = (half_t*)p; p += DM*DM*2;
    half_t* W1h = (half_t*)p; p += (long long)FFD*DM*2;
    half_t* W2h = (half_t*)p; p += (long long)DM*FFD*2;
    half_t* W3h = (half_t*)p; p += 512*DM*2;
    half_t* W4h = (half_t*)p; p += 128*512*2;
    float*  b4p = (float*)p;  p += 128*4;

    float*  Xf   = (float*)R_A;
    float*  Pff  = (float*)R_A;             // FFN2 split-K partials [2][8192][1024] (Xf dead)
    half_t* Xh   = (half_t*)R_B;
    half_t* h2h  = (half_t*)R_B;
    half_t* Qh   = (half_t*)R_C;
    half_t* h1h  = (half_t*)R_C;
    half_t* Kt   = (half_t*)R_D;            // [8][1024][2048]
    half_t* Vt   = (half_t*)R_D2;
    half_t* f1h  = (half_t*)R_D;            // [8192,4096] chunk (Kt+Vt dead)
    float*  usum = (float*)R_E;             // x + u (fp32) -> h1f in-place
    float*  h1f  = (float*)R_E;
    half_t* ktv2 = (half_t*)R_F;            // [8][1024][1024]
    half_t* M2t  = (half_t*)(R_F + (long long)NB*DM*DM*2);
    half_t* l1h  = (half_t*)R_F;            // [16384,512]
    float*  LOG  = (float*)R_G;
    float*  out  = (float*)d_out;

    dim3 blk(256);

    // ---- weight transpose fp32 [K,N] -> fp16 [Npad,K]; PE table ---------
    transpose_h_kernel<<<dim3(32, 32),  blk, 0, stream>>>(Wq, Wqh, DM, DM, DM);
    transpose_h_kernel<<<dim3(32, 32),  blk, 0, stream>>>(Wk, Wkh, DM, DM, DM);
    transpose_h_kernel<<<dim3(32, 32),  blk, 0, stream>>>(Wv, Wvh, DM, DM, DM);
    transpose_h_kernel<<<dim3(32, 32),  blk, 0, stream>>>(Wu, Wuh, DM, DM, DM);
    transpose_h_kernel<<<dim3(128, 32), blk, 0, stream>>>(W1, W1h, DM, FFD, FFD);
    transpose_h_kernel<<<dim3(32, 128), blk, 0, stream>>>(W2, W2h, FFD, DM, DM);
    transpose_h_kernel<<<dim3(16, 32),  blk, 0, stream>>>(W3, W3h, DM, 512, 512);
    transpose_h_kernel<<<dim3(4, 16),   blk, 0, stream>>>(W4, W4h, 512, NCAT, 128);
    pad_bias_kernel<<<1, 128, 0, stream>>>(b4, b4p);
    pe_kernel<<<(SEQ * DM + 255) / 256, blk, 0, stream>>>(pe);

    // ---- x = emb[idx] + pe  (gather, float4) ----------------------------
    embed_pos_kernel<<<(T_TOK * DM / 4 + 255) / 256, blk, 0, stream>>>(idx, emb, pe, Xf, Xh);

    // ---- QKV: Q normal; K,V transposed [b][dm][seq] ---------------------
    gemm_nt<1><<<dim3(8, 128, 1), blk, 0, stream>>>(Xh, Wqh, bq, nullptr, Qh,
        T_TOK, DM, DM, DM, 0, 0, 0, 0, 0, 0, 0, 1.f, 0);
    gemm_nt<2><<<dim3(8, 128, 1), blk, 0, stream>>>(Xh, Wkh, bk, nullptr, Kt,
        T_TOK, DM, DM, DM, 0, 0, 0, 0, 0, 0, 0, 1.f, 0);
    gemm_nt<2><<<dim3(8, 128, 1), blk, 0, stream>>>(Xh, Wvh, bv, nullptr, Vt,
        T_TOK, DM, DM, DM, 0, 0, 0, 0, 0, 0, 0, 1.f, 0);

    // ---- ktv2[b][k][v] = NT(Kt[b], Vt[b]) * 0.125 -----------------------
    gemm_nt<1><<<dim3(8, 8, NB), blk, 0, stream>>>(Kt, Vt, nullptr, nullptr, ktv2,
        DM, DM, SEQ, SEQ, (long long)DM * SEQ, (long long)DM * SEQ, (long long)DM * DM,
        0, 0, 0, 0, 0.125f, 0);

    // ---- M2t[b][n][k] = NT(Wuh, ktv2[b]) --------------------------------
    gemm_nt<1><<<dim3(8, 8, NB), blk, 0, stream>>>(Wuh, ktv2, nullptr, nullptr, M2t,
        DM, DM, DM, DM, 0, (long long)DM * DM, (long long)DM * DM,
        0, 0, 0, 0, 1.f, 0);

    // ---- usum = NT(Q, M2t[b]) + bu + Xf  (fp32, residual fused) ---------
    gemm_nt<0><<<dim3(8, 16, NB), blk, 0, stream>>>(Qh, M2t, bu, Xf, usum,
        SEQ, DM, DM, DM, (long long)SEQ * DM, (long long)DM * DM, (long long)SEQ * DM,
        0, 0, 0, 0, 1.f, 0);

    // ---- h1 = LN(usum): in-place fp32 + fp16 ----------------------------
    add_ln_kernel<<<T_TOK, blk, 0, stream>>>(usum, nullptr, nullptr, nullptr,
                                             g1, be1, h1f, h1h);

    // ---- FFN, 2 chunks of 8192 rows; FFN2 split-K=2, sum fused into LN --
    for (int c = 0; c < 2; c++) {
        const half_t* h1c = h1h + (long long)c * 8192 * DM;
        gemm_nt<1><<<dim3(32, 64, 1), blk, 0, stream>>>(h1c, W1h, b1, nullptr, f1h,
            8192, FFD, DM, DM, 0, 0, 0, 0, 0, 0, 0, 1.f, 1);
        // split-K=2: kz=0 -> Pff[0], kz=1 -> Pff[1]; b2 folded into LN below
        gemm_nt<0><<<dim3(8, 64, 2), blk, 0, stream>>>(f1h, W2h, nullptr, nullptr, Pff,
            8192, DM, 2048, FFD, 0, 0, 0,
            2048, 2048, (long long)8192 * DM, 1, 1.f, 0);
        add_ln_kernel<<<8192, blk, 0, stream>>>(h1f + (long long)c * 8192 * DM,
            Pff, Pff + (long long)8192 * DM, b2, g2, be2,
            nullptr, h2h + (long long)c * 8192 * DM);
    }

    // ---- head: l1 = relu(h2@W3+b3) fp16; LOG = l1@W4p + b4p (N=128) -----
    gemm_nt<1><<<dim3(4, 128, 1), blk, 0, stream>>>(h2h, W3h, b3, nullptr, l1h,
        T_TOK, 512, DM, DM, 0, 0, 0, 0, 0, 0, 0, 1.f, 1);
    gemm_nt<0><<<dim3(1, 128, 1), blk, 0, stream>>>(l1h, W4h, b4p, nullptr, LOG,
        T_TOK, 128, 512, 512, 0, 0, 0, 0, 0, 0, 0, 1.f, 0);

    // ---- out = sigmoid(LN75(logits)) ------------------------------------
    ln75_sigmoid_kernel<<<T_TOK, 64, 0, stream>>>(LOG, g3, be3, out);
}

// Round 3
// 1007.317 us; speedup vs baseline: 1.1281x; 1.1281x over previous
//
#include <hip/hip_runtime.h>
#include <hip/hip_fp16.h>
#include <math.h>

// Problem constants
#define DM    1024
#define FFD   4096
#define VOCAB 32000
#define NCAT  75
#define UNK_IDX 1
#define EPS   1e-5f
#define NB    8
#define SEQ   2048
#define T_TOK (NB*SEQ)   // 16384 tokens

using u16   = unsigned short;
using half_t = _Float16;
using half8 = __attribute__((ext_vector_type(8))) _Float16;  // MFMA A/B frag (4 VGPRs)
using f32x4 = __attribute__((ext_vector_type(4))) float;     // MFMA C/D frag

struct alignas(8) h4 { half_t s[4]; };

// async global->LDS, 16 B per lane; LDS dest = wave-uniform base + lane*16
__device__ __forceinline__ void async16(const half_t* g, half_t* l) {
    __builtin_amdgcn_global_load_lds(
        (const __attribute__((address_space(1))) void*)g,
        (__attribute__((address_space(3))) void*)l,
        16, 0, 0);
}

#define VMW(n) asm volatile("s_waitcnt vmcnt(" #n ")" ::: "memory")
#define LGKM0()                                            \
    do {                                                   \
        asm volatile("s_waitcnt lgkmcnt(0)" ::: "memory"); \
        __builtin_amdgcn_sched_barrier(0);                 \
    } while (0)

// ---------------------------------------------------------------------------
// Positional-encoding table [SEQ][DM] fp32 (computed once, shared by batch)
// ---------------------------------------------------------------------------
__global__ __launch_bounds__(256)
void pe_kernel(float* __restrict__ pe)
{
    int gid = blockIdx.x * blockDim.x + threadIdx.x;   // over SEQ*DM
    if (gid >= SEQ * DM) return;
    int dcol = gid & (DM - 1);
    int t    = gid >> 10;
    int p = dcol >> 1;
    float power = (float)p / 512.0f;
    float denom = powf(10000.0f, power);
    float ang = (float)t / denom;
    pe[gid] = (dcol & 1) ? cosf(ang) : sinf(ang);
}

// ---------------------------------------------------------------------------
// Embedding gather + PE add -> Xf (fp32) and Xh (fp16), float4-vectorized
// ---------------------------------------------------------------------------
__global__ __launch_bounds__(256)
void embed_pos_kernel(const int* __restrict__ idx,
                      const float* __restrict__ emb,
                      const float* __restrict__ pe,
                      float* __restrict__ xf, half_t* __restrict__ xh)
{
    int gid4 = blockIdx.x * blockDim.x + threadIdx.x;  // over T_TOK*DM/4
    if (gid4 >= T_TOK * DM / 4) return;
    int tok = gid4 >> 8;            // DM/4 = 256 float4 per token
    int c4  = (gid4 & 255) << 2;
    int t   = tok & (SEQ - 1);
    int id = idx[tok];
    if (id >= VOCAB || id < 0) id = UNK_IDX;
    float4 e = *(const float4*)(emb + (long long)id * DM + c4);
    float4 q = *(const float4*)(pe + (long long)t * DM + c4);
    float4 v = make_float4(e.x + q.x, e.y + q.y, e.z + q.z, e.w + q.w);
    *(float4*)(xf + (long long)tok * DM + c4) = v;
    h4 pk = {{(half_t)v.x, (half_t)v.y, (half_t)v.z, (half_t)v.w}};
    *(h4*)(xh + (long long)tok * DM + c4) = pk;
}

// ---------------------------------------------------------------------------
// Weight transpose + fp32->fp16: in [K,N] fp32 -> out [Npad,K] fp16
// ---------------------------------------------------------------------------
__global__ __launch_bounds__(256)
void transpose_h_kernel(const float* __restrict__ in, half_t* __restrict__ out,
                        int K, int N, int Npad)
{
    __shared__ float t[32][33];
    int n0 = blockIdx.x * 32, k0 = blockIdx.y * 32;
    int tx = threadIdx.x & 31, ty = threadIdx.x >> 5;   // ty 0..7
#pragma unroll
    for (int i = 0; i < 4; i++) {
        int k = k0 + ty + i * 8, n = n0 + tx;
        t[ty + i * 8][tx] = (k < K && n < N) ? in[(long long)k * N + n] : 0.f;
    }
    __syncthreads();
#pragma unroll
    for (int i = 0; i < 4; i++) {
        int n = n0 + ty + i * 8, k = k0 + tx;
        if (n < Npad && k < K)
            out[(long long)n * K + k] = (half_t)t[tx][ty + i * 8];
    }
}

// pad b4 [75] -> b4p [128]
__global__ __launch_bounds__(128)
void pad_bias_kernel(const float* __restrict__ b, float* __restrict__ bp)
{
    int i = threadIdx.x;
    bp[i] = (i < NCAT) ? b[i] : 0.f;
}

// ---------------------------------------------------------------------------
// fp16 MFMA NT GEMM, software-pipelined dbuf K-loop (m97 shape) + LDS-staged
// coalesced epilogue. (Round-0 form; used for odd shapes / transposed out.)
//   C = scale*(A @ B^T) + bias [+ resid] [,relu]; fp16 in, fp32 acc.
//   128x128 tile, BK=32, 256 thr = 4 waves (2x2), 4x4 16x16x32 MFMA/wave.
// OUT_MODE: 0 = fp32 [M,N] at C + z*sC (+resid); 1 = fp16 [M,N];
//           2 = fp16 KV-transposed [b][n][t], b=row>>11, t=row&2047.
// ---------------------------------------------------------------------------
template<int OUT_MODE>
__global__ __launch_bounds__(256)
void gemm_nt(const half_t* __restrict__ A, const half_t* __restrict__ B,
             const float* __restrict__ bias, const float* __restrict__ resid,
             void* __restrict__ Cout,
             int M, int N, int K, int ld,
             long long sA, long long sB, long long sC,
             float scale, int do_relu)
{
    A += (long long)blockIdx.z * sA;
    B += (long long)blockIdx.z * sB;
    const int tid  = threadIdx.x;
    const int lane = tid & 63;
    const int w    = tid >> 6;          // wave 0..3
    const int wm   = w >> 1, wn = w & 1;
    const long long row0 = (long long)blockIdx.y * 128;
    const long long col0 = (long long)blockIdx.x * 128;

    __shared__ half_t smem[4 * 4096];   // 2 tensors x 2 buffers x 8 KB
    half_t* const As = smem;
    half_t* const Bs = smem + 2 * 4096;

    f32x4 acc[4][4];
    const f32x4 zero = {0.f, 0.f, 0.f, 0.f};
#pragma unroll
    for (int i = 0; i < 4; i++)
#pragma unroll
        for (int j = 0; j < 4; j++) acc[i][j] = zero;

    const int ldrow = lane >> 2;                                  // staging row in 16-row chunk
    const int swcol = (((lane & 3) << 3)) ^ ((ldrow & 3) << 3);   // swizzled source col
    const int fr    = lane & 15;                                  // fragment row
    const int kk8   = (lane >> 4) << 3;                           // fragment k offset

    const int KT = K / 32;

#define ISSUE(k0, buf)                                                         \
    {                                                                          \
        _Pragma("unroll")                                                      \
        for (int it = 0; it < 2; ++it) {                                       \
            int rb = (it * 4 + w) * 16;                                        \
            long long ao = (row0 + rb + ldrow) * (long long)ld + (k0) + swcol; \
            long long bo = (col0 + rb + ldrow) * (long long)ld + (k0) + swcol; \
            async16(A + ao, As + (buf) * 4096 + rb * 32);                      \
            async16(B + bo, Bs + (buf) * 4096 + rb * 32);                      \
        }                                                                      \
    }

    ISSUE(0, 0);
    for (int kt = 0; kt < KT; ++kt) {
        const int cur = kt & 1;
        __syncthreads();                 // cur buffer ready; prev consumers done
        if (kt + 1 < KT) ISSUE((kt + 1) * 32, cur ^ 1);

        half8 af[4], bf[4];
#pragma unroll
        for (int i = 0; i < 4; ++i) {
            int r   = wm * 64 + i * 16 + fr;
            int off = cur * 4096 + r * 32 + (kk8 ^ ((r & 3) << 3));
            af[i] = *(const half8*)(As + off);
        }
#pragma unroll
        for (int j = 0; j < 4; ++j) {
            int r   = wn * 64 + j * 16 + fr;
            int off = cur * 4096 + r * 32 + (kk8 ^ ((r & 3) << 3));
            bf[j] = *(const half8*)(Bs + off);
        }
#pragma unroll
        for (int i = 0; i < 4; ++i)
#pragma unroll
            for (int j = 0; j < 4; ++j)
                acc[i][j] = __builtin_amdgcn_mfma_f32_16x16x32_f16(
                    af[i], bf[j], acc[i][j], 0, 0, 0);
    }
#undef ISSUE

    // ---- LDS-staged epilogue ------------------------------------------------
    float* ls = (float*)smem;           // 32*132*4 = 16.9 KB <= 32 KB
    const int ldp = 132;
    const int qr = (lane >> 4) * 4;
    const int lc = lane & 15;
    float bvj[4];
#pragma unroll
    for (int j = 0; j < 4; ++j)
        bvj[j] = bias ? bias[col0 + wn * 64 + j * 16 + lc] : 0.f;
    const float* rz = (OUT_MODE == 0 && resid) ? resid + (long long)blockIdx.z * sC : nullptr;

#pragma unroll
    for (int i = 0; i < 4; ++i) {
        __syncthreads();                // LDS free (K-loop or previous chunk done)
#pragma unroll
        for (int j = 0; j < 4; ++j) {
            int col = wn * 64 + j * 16 + lc;
#pragma unroll
            for (int r = 0; r < 4; ++r) {
                float f = acc[i][j][r] * scale + bvj[j];
                if (do_relu) f = fmaxf(f, 0.f);
                ls[(wm * 16 + qr + r) * ldp + col] = f;
            }
        }
        __syncthreads();
        if (OUT_MODE == 2) {
#pragma unroll
            for (int rep = 0; rep < 4; ++rep) {
                int idx = rep * 256 + tid;      // 0..1023
                int n   = idx >> 3;
                int k   = idx & 7;
                int lr0 = k * 4;
                h4 pk;
                long long arow0 = (lr0 < 16 ? 0 : 48) + i * 16 + lr0;
#pragma unroll
                for (int r = 0; r < 4; ++r)
                    pk.s[r] = (half_t)ls[(lr0 + r) * ldp + n];
                long long gr = row0 + arow0;    // 4 consecutive tokens
                int b  = (int)(gr >> 11);
                int tl = (int)(gr & (SEQ - 1));
                half_t* C = (half_t*)Cout;
                *(h4*)(C + (long long)b * N * SEQ + (col0 + n) * SEQ + tl) = pk;
            }
        } else {
#pragma unroll
            for (int rep = 0; rep < 4; ++rep) {
                int idx = rep * 256 + tid;      // 0..1023
                int lr  = idx >> 5;             // 0..31
                int c4  = (idx & 31) << 2;      // col offset 0..124
                long long arow = (lr < 16 ? 0 : 48) + i * 16 + lr;
                float4 v = *(float4*)&ls[lr * ldp + c4];
                long long base = (row0 + arow) * N + col0 + c4;
                if (OUT_MODE == 0) {
                    float* C = (float*)Cout + blockIdx.z * sC;
                    if (rz) {
                        float4 x = *(const float4*)(rz + base);
                        v.x += x.x; v.y += x.y; v.z += x.z; v.w += x.w;
                    }
                    *(float4*)(C + base) = v;
                } else {
                    half_t* C = (half_t*)Cout + blockIdx.z * sC;
                    h4 pk = {{(half_t)v.x, (half_t)v.y, (half_t)v.z, (half_t)v.w}};
                    *(h4*)(C + base) = pk;
                }
            }
        }
    }
}

// ---------------------------------------------------------------------------
// 256x256 8-wave 4-phase counted-vmcnt fp16 NT GEMM (m201-template sync:
// barrier -> lgkmcnt(0) -> sched_barrier(0) -> setprio/MFMA -> barrier).
// BK=64, 512 thr, waves 2Mx4N, per-wave C = 128x64.
// LDS: per tensor [2 buf][2 ksub][256 rows][32 halves] = 32 KB -> 128 KB tot.
//   ksub-plane rows are 64 B: a 16-row b128 frag read is a contiguous 1 KB
//   block -> conflict-free with LINEAR layout (gload_lds dest stays linear).
// Schedule per K-tile t (buf = t&1): 4 phases; each phase issues ONE granule
//   (A-k0 / B-k0 / A-k1 / B-k1 of tile t+1) = 2 gload_lds; vmcnt(4) at odd
//   phases only (drains exactly the granules needed one phase later, keeps
//   4 loads in flight); vmcnt never 0 in the loop. Clamped tail stages keep
//   the wait arithmetic uniform; vmcnt(0) once before the epilogue.
// Requires M%256==0, N%256==0, K%64==0. Grid (N/256, M/256, z).
// OUT_MODE: 0 = fp32 [+resid]; 1 = fp16. z decode: kz = z & ((1<<ksh)-1)
//   K-split (A += kz*sKA, B += kz*sKB, C += kz*sKC), zb = z >> ksh batch.
// ---------------------------------------------------------------------------
template<int OUT_MODE>
__global__ __launch_bounds__(512, 2)
void gemm256(const half_t* __restrict__ A, const half_t* __restrict__ B,
             const float* __restrict__ bias, const float* __restrict__ resid,
             void* __restrict__ Cout,
             int N, int K, int ld,
             long long sA, long long sB, long long sC,
             long long sKA, long long sKB, long long sKC, int ksh,
             float scale, int do_relu)
{
    const int kz       = (int)(blockIdx.z & ((1u << ksh) - 1u));
    const long long zb = (long long)(blockIdx.z >> ksh);
    A += zb * sA + (long long)kz * sKA;
    B += zb * sB + (long long)kz * sKB;

    // XCD-bijective chunked swizzle (nxy % 8 == 0 at all call sites)
    int bx = blockIdx.x, by = blockIdx.y;
    const int nxy = gridDim.x * gridDim.y;
    if ((nxy & 7) == 0) {
        const int orig = by * gridDim.x + bx;
        const int cpx  = nxy >> 3;
        const int wg   = (orig & 7) * cpx + (orig >> 3);
        bx = wg % gridDim.x;
        by = wg / gridDim.x;
    }
    const long long row0 = (long long)by * 256;
    const long long col0 = (long long)bx * 256;

    const int tid  = threadIdx.x;
    const int lane = tid & 63;
    const int w    = tid >> 6;          // wave 0..7
    const int wm   = w >> 2, wn = w & 3;
    const int fr   = lane & 15;
    const int kk8  = (lane >> 4) << 3;

    __shared__ half_t smem[65536];      // 128 KB
    half_t* const As = smem;            // [2 buf][2 ksub][8192]
    half_t* const Bs = smem + 32768;

    f32x4 acc[8][4];
    const f32x4 zero = {0.f, 0.f, 0.f, 0.f};
#pragma unroll
    for (int i = 0; i < 8; i++)
#pragma unroll
        for (int j = 0; j < 4; j++) acc[i][j] = zero;

    // staging geometry: lane covers plane row it*128 + w*16 + (lane>>2),
    // halves (lane&3)*8; LDS dest (uniform per wave) = plane + it*4096 + w*512
    const int srow = w * 16 + (lane >> 2);
    const int scol = (lane & 3) << 3;

#define STAGE(G, plane, rb, kb)                                                   \
    {                                                                             \
        _Pragma("unroll")                                                         \
        for (int it_ = 0; it_ < 2; ++it_) {                                       \
            async16((G) + ((rb) + it_ * 128 + srow) * (long long)ld + (kb) + scol,\
                    (plane) + it_ * 4096 + w * 512);                              \
        }                                                                         \
    }
#define RDA(base_, roff_)                                                         \
    _Pragma("unroll")                                                             \
    for (int q_ = 0; q_ < 4; ++q_)                                                \
        af[q_] = *(const half8*)((base_) + ((roff_) + q_ * 16 + fr) * 32 + kk8);
#define RDB(base_)                                                                \
    _Pragma("unroll")                                                             \
    for (int q_ = 0; q_ < 4; ++q_)                                                \
        bf[q_] = *(const half8*)((base_) + (wn * 64 + q_ * 16 + fr) * 32 + kk8);
#define MM16(o_)                                                                  \
    _Pragma("unroll")                                                             \
    for (int mi_ = 0; mi_ < 4; ++mi_)                                             \
    _Pragma("unroll")                                                             \
    for (int ni_ = 0; ni_ < 4; ++ni_)                                             \
        acc[(o_) + mi_][ni_] = __builtin_amdgcn_mfma_f32_16x16x32_f16(            \
            af[mi_], bf[ni_], acc[(o_) + mi_][ni_], 0, 0, 0);
#define MFMA_PHASE(o_)                                      \
    __builtin_amdgcn_s_barrier();                           \
    LGKM0();                                                \
    __builtin_amdgcn_s_setprio(1);                          \
    MM16(o_);                                               \
    __builtin_amdgcn_s_setprio(0);                          \
    __builtin_amdgcn_s_barrier();

    const int KT = K >> 6;

    // prologue: K-tile 0 into buf 0 (order A-k0, B-k0, A-k1, B-k1)
    STAGE(A, As,        row0, 0);
    STAGE(B, Bs,        col0, 0);
    STAGE(A, As + 8192, row0, 32);
    STAGE(B, Bs + 8192, col0, 32);
    VMW(4);             // A-k0, B-k0 landed (per wave; barrier makes it global)
    __builtin_amdgcn_s_barrier();

    half8 af[4], bf[4];
    for (int t = 0; t < KT; ++t) {
        const int db = (t & 1) << 14;   // 16384-half buf offset
        const int nb = 16384 - db;
        const half_t* Ap0 = As + db;
        const half_t* Ap1 = As + db + 8192;
        const half_t* Bp0 = Bs + db;
        const half_t* Bp1 = Bs + db + 8192;
        const int kn = (t + 1 < KT ? t + 1 : t) << 6;   // clamped tail stage

        // phase 0: ksub0, rows mi 0..3
        RDA(Ap0, wm * 128); RDB(Bp0);
        STAGE(A, As + nb, row0, kn);
        MFMA_PHASE(0);
        // phase 1: ksub0, rows mi 4..7 (bf reused)
        RDA(Ap0, wm * 128 + 64);
        STAGE(B, Bs + nb, col0, kn);
        VMW(4);                         // drain A-k1,B-k1 of current tile
        MFMA_PHASE(4);
        // phase 2: ksub1, rows mi 0..3
        RDA(Ap1, wm * 128); RDB(Bp1);
        STAGE(A, As + nb + 8192, row0, kn + 32);
        MFMA_PHASE(0);
        // phase 3: ksub1, rows mi 4..7
        RDA(Ap1, wm * 128 + 64);
        STAGE(B, Bs + nb + 8192, col0, kn + 32);
        VMW(4);                         // drain A-k0,B-k0 of next tile
        MFMA_PHASE(4);
    }
#undef STAGE
#undef RDA
#undef RDB
#undef MM16
#undef MFMA_PHASE

    // ---- epilogue: 4 chunks of 64 rows x 256 cols via LDS ----------------
    VMW(0);                           // drain dummy tail stages before reuse
    __syncthreads();
    float* const ls = (float*)smem;   // [64][268] f32 = 68.6 KB
    const int ldp = 268;
    const int qr = (lane >> 4) * 4;
    const int lc = lane & 15;
    float bvn[4];
#pragma unroll
    for (int ni = 0; ni < 4; ++ni)
        bvn[ni] = bias ? bias[col0 + wn * 64 + ni * 16 + lc] : 0.f;
    const float* rz = (OUT_MODE == 0 && resid) ? resid + zb * sC : nullptr;

#pragma unroll
    for (int i = 0; i < 4; ++i) {
        if (i) __syncthreads();
#pragma unroll
        for (int h = 0; h < 2; ++h) {
            const int mi = 2 * i + h;
#pragma unroll
            for (int ni = 0; ni < 4; ++ni) {
#pragma unroll
                for (int r = 0; r < 4; ++r) {
                    float f = acc[mi][ni][r] * scale + bvn[ni];
                    if (do_relu) f = fmaxf(f, 0.f);
                    ls[(wm * 32 + h * 16 + qr + r) * ldp + wn * 64 + ni * 16 + lc] = f;
                }
            }
        }
        __syncthreads();
#pragma unroll
        for (int rep = 0; rep < 8; ++rep) {
            int idx2 = rep * 512 + tid;            // 0..4095
            int r  = idx2 >> 6;                    // 0..63
            int c4 = (idx2 & 63) << 2;             // 0..252
            long long grow = row0 + (r < 32 ? i * 32 + r : 128 + i * 32 + (r - 32));
            long long base = grow * N + col0 + c4;
            float4 v = *(float4*)&ls[r * ldp + c4];
            if (OUT_MODE == 0) {
                float* C = (float*)Cout + zb * sC + (long long)kz * sKC;
                if (rz) {
                    float4 x = *(const float4*)(rz + base);
                    v.x += x.x; v.y += x.y; v.z += x.z; v.w += x.w;
                }
                *(float4*)(C + base) = v;
            } else {
                half_t* C = (half_t*)Cout + zb * sC;
                h4 pk = {{(half_t)v.x, (half_t)v.y, (half_t)v.z, (half_t)v.w}};
                *(h4*)(C + base) = pk;
            }
        }
    }
}

// ---------------------------------------------------------------------------
// LN(X [+ Y] [+ Z] [+ cb]) * g + b over DM=1024, float4-vectorized, one
// block/row. cb is a per-column [DM] bias (b2 folded out of split-K GEMM).
// In-place safe (outf may alias X): all reads precede writes.
// ---------------------------------------------------------------------------
__global__ __launch_bounds__(256)
void add_ln_kernel(const float* __restrict__ X, const float* __restrict__ Y,
                   const float* __restrict__ Z, const float* __restrict__ cb,
                   const float* __restrict__ g, const float* __restrict__ b,
                   float* __restrict__ outf, half_t* __restrict__ outh)
{
    int row = blockIdx.x;
    int tid = threadIdx.x;
    float4 v = ((const float4*)(X + (long long)row * DM))[tid];
    if (Y) {
        float4 y = ((const float4*)(Y + (long long)row * DM))[tid];
        v.x += y.x; v.y += y.y; v.z += y.z; v.w += y.w;
    }
    if (Z) {
        float4 z = ((const float4*)(Z + (long long)row * DM))[tid];
        v.x += z.x; v.y += z.y; v.z += z.z; v.w += z.w;
    }
    if (cb) {
        float4 c = ((const float4*)cb)[tid];
        v.x += c.x; v.y += c.y; v.z += c.z; v.w += c.w;
    }
    float s  = v.x + v.y + v.z + v.w;
    float s2 = v.x * v.x + v.y * v.y + v.z * v.z + v.w * v.w;
#pragma unroll
    for (int o = 1; o < 64; o <<= 1) {
        s  += __shfl_xor(s,  o, 64);
        s2 += __shfl_xor(s2, o, 64);
    }
    __shared__ float rs[4], rs2[4], stats[2];
    int wid = tid >> 6;
    if ((tid & 63) == 0) { rs[wid] = s; rs2[wid] = s2; }
    __syncthreads();
    if (tid == 0) {
        float S  = rs[0] + rs[1] + rs[2] + rs[3];
        float S2 = rs2[0] + rs2[1] + rs2[2] + rs2[3];
        float mean = S / (float)DM;
        float var  = S2 / (float)DM - mean * mean;   // biased var == jnp.var
        stats[0] = mean;
        stats[1] = rsqrtf(var + EPS);
    }
    __syncthreads();
    float mean = stats[0], rstd = stats[1];
    float4 gg = ((const float4*)g)[tid];
    float4 bb = ((const float4*)b)[tid];
    float4 o;
    o.x = (v.x - mean) * rstd * gg.x + bb.x;
    o.y = (v.y - mean) * rstd * gg.y + bb.y;
    o.z = (v.z - mean) * rstd * gg.z + bb.z;
    o.w = (v.w - mean) * rstd * gg.w + bb.w;
    if (outf) ((float4*)(outf + (long long)row * DM))[tid] = o;
    h4 pk = {{(half_t)o.x, (half_t)o.y, (half_t)o.z, (half_t)o.w}};
    *(h4*)(outh + (long long)row * DM + tid * 4) = pk;
}

// ---------------------------------------------------------------------------
// out[row,:] = sigmoid(LN75(L[row,0:75]) * g + b); L leading dim 128
// ---------------------------------------------------------------------------
__global__ __launch_bounds__(64)
void ln75_sigmoid_kernel(const float* __restrict__ L,
                         const float* __restrict__ g, const float* __restrict__ b,
                         float* __restrict__ out)
{
    int row = blockIdx.x;
    int t   = threadIdx.x;
    const float* lr = L + (long long)row * 128;
    float e0 = (t < NCAT) ? lr[t] : 0.f;
    float e1 = (t + 64 < NCAT) ? lr[t + 64] : 0.f;
    float s  = e0 + e1;
    float s2 = e0 * e0 + e1 * e1;
#pragma unroll
    for (int o = 1; o < 64; o <<= 1) {
        s  += __shfl_xor(s,  o, 64);
        s2 += __shfl_xor(s2, o, 64);
    }
    float mean = s / (float)NCAT;
    float var  = s2 / (float)NCAT - mean * mean;
    float rstd = rsqrtf(var + EPS);
    if (t < NCAT) {
        float z = (e0 - mean) * rstd * g[t] + b[t];
        out[(long long)row * NCAT + t] = 1.f / (1.f + expf(-z));
    }
    if (t + 64 < NCAT) {
        float z = (e1 - mean) * rstd * g[t + 64] + b[t + 64];
        out[(long long)row * NCAT + t + 64] = 1.f / (1.f + expf(-z));
    }
}

// ---------------------------------------------------------------------------
// Orchestration. Attention fully folded:
//   (QK^T/8)V Wu + bu + x == Q @ M2t^T + bu + x,
//   ktv2[b][k][v] = 0.125 * sum_t K[t,k]V[t,v]  = NT(Kt, Vt) * 0.125
//   M2t[b][n][k]  = sum_v Wu[v,n] ktv2[k][v]    = NT(Wuh, ktv2[b])
//   usum          = NT256(Q, M2t[b]) + bu + Xf  (fp32, residual fused)
// Big regular GEMMs (Q, FFN1, FFN2 split-K=2, usum) use gemm256; the rest
// (K/V transposed-out, ktv2, M2t, W3, W4) use the 128x128 kernel.
// ---------------------------------------------------------------------------
extern "C" void kernel_launch(void* const* d_in, const int* in_sizes, int n_in,
                              void* d_out, int out_size, void* d_ws, size_t ws_size,
                              hipStream_t stream)
{
    const int*   idx = (const int*)  d_in[0];
    const float* emb = (const float*)d_in[1];
    const float* Wq  = (const float*)d_in[2];
    const float* bq  = (const float*)d_in[3];
    const float* Wk  = (const float*)d_in[4];
    const float* bk  = (const float*)d_in[5];
    const float* Wv  = (const float*)d_in[6];
    const float* bv  = (const float*)d_in[7];
    const float* Wu  = (const float*)d_in[8];
    const float* bu  = (const float*)d_in[9];
    const float* g1  = (const float*)d_in[10];
    const float* be1 = (const float*)d_in[11];
    const float* W1  = (const float*)d_in[12];
    const float* b1  = (const float*)d_in[13];
    const float* W2  = (const float*)d_in[14];
    const float* b2  = (const float*)d_in[15];
    const float* g2  = (const float*)d_in[16];
    const float* be2 = (const float*)d_in[17];
    const float* W3  = (const float*)d_in[18];
    const float* b3  = (const float*)d_in[19];
    const float* W4  = (const float*)d_in[20];
    const float* b4  = (const float*)d_in[21];
    const float* g3  = (const float*)d_in[22];
    const float* be3 = (const float*)d_in[23];

    const long long TD  = (long long)T_TOK * DM;       // 16.78M
    char* p = (char*)d_ws;
    char* R_A = p; p += TD * 4;
    char* R_B = p; p += TD * 2;
    char* R_C = p; p += TD * 2;
    char* R_D = p; p += TD * 2;                        // 32 MB (Kt) ...
    char* R_D2 = p; p += TD * 2;                       // 32 MB (Vt); R_D..R_D2 = 64MB f1h
    char* R_E = p; p += TD * 4;
    char* R_F = p; p += (long long)NB * DM * DM * 4;   // 32 MB
    char* R_G = p; p += (long long)T_TOK * 128 * 4;    // 8 MB
    float* pe = (float*)p; p += (long long)SEQ * DM * 4; // 8 MB
    half_t* Wqh = (half_t*)p; p += DM*DM*2;
    half_t* Wkh = (half_t*)p; p += DM*DM*2;
    half_t* Wvh = (half_t*)p; p += DM*DM*2;
    half_t* Wuh = (half_t*)p; p += DM*DM*2;
    half_t* W1h = (half_t*)p; p += (long long)FFD*DM*2;
    half_t* W2h = (half_t*)p; p += (long long)DM*FFD*2;
    half_t* W3h = (half_t*)p; p += 512*DM*2;
    half_t* W4h = (half_t*)p; p += 128*512*2;
    float*  b4p = (float*)p;  p += 128*4;

    float*  Xf   = (float*)R_A;
    float*  Pff  = (float*)R_A;             // FFN2 split-K partials [2][8192][1024] (Xf dead)
    half_t* Xh   = (half_t*)R_B;
    half_t* h2h  = (half_t*)R_B;
    half_t* Qh   = (half_t*)R_C;
    half_t* h1h  = (half_t*)R_C;
    half_t* Kt   = (half_t*)R_D;            // [8][1024][2048]
    half_t* Vt   = (half_t*)R_D2;
    half_t* f1h  = (half_t*)R_D;            // [8192,4096] chunk (Kt+Vt dead)
    float*  usum = (float*)R_E;             // x + u (fp32) -> h1f in-place
    float*  h1f  = (float*)R_E;
    half_t* ktv2 = (half_t*)R_F;            // [8][1024][1024]
    half_t* M2t  = (half_t*)(R_F + (long long)NB*DM*DM*2);
    half_t* l1h  = (half_t*)R_F;            // [16384,512]
    float*  LOG  = (float*)R_G;
    float*  out  = (float*)d_out;

    dim3 blk(256);
    dim3 blk5(512);

    // ---- weight transpose fp32 [K,N] -> fp16 [Npad,K]; PE table ---------
    transpose_h_kernel<<<dim3(32, 32),  blk, 0, stream>>>(Wq, Wqh, DM, DM, DM);
    transpose_h_kernel<<<dim3(32, 32),  blk, 0, stream>>>(Wk, Wkh, DM, DM, DM);
    transpose_h_kernel<<<dim3(32, 32),  blk, 0, stream>>>(Wv, Wvh, DM, DM, DM);
    transpose_h_kernel<<<dim3(32, 32),  blk, 0, stream>>>(Wu, Wuh, DM, DM, DM);
    transpose_h_kernel<<<dim3(128, 32), blk, 0, stream>>>(W1, W1h, DM, FFD, FFD);
    transpose_h_kernel<<<dim3(32, 128), blk, 0, stream>>>(W2, W2h, FFD, DM, DM);
    transpose_h_kernel<<<dim3(16, 32),  blk, 0, stream>>>(W3, W3h, DM, 512, 512);
    transpose_h_kernel<<<dim3(4, 16),   blk, 0, stream>>>(W4, W4h, 512, NCAT, 128);
    pad_bias_kernel<<<1, 128, 0, stream>>>(b4, b4p);
    pe_kernel<<<(SEQ * DM + 255) / 256, blk, 0, stream>>>(pe);

    // ---- x = emb[idx] + pe  (gather, float4) ----------------------------
    embed_pos_kernel<<<(T_TOK * DM / 4 + 255) / 256, blk, 0, stream>>>(idx, emb, pe, Xf, Xh);

    // ---- QKV: Q via 256-tile; K,V transposed [b][dm][seq] via 128-tile --
    gemm256<1><<<dim3(4, 64, 1), blk5, 0, stream>>>(Xh, Wqh, bq, nullptr, Qh,
        DM, DM, DM, 0, 0, 0, 0, 0, 0, 0, 1.f, 0);
    gemm_nt<2><<<dim3(8, 128, 1), blk, 0, stream>>>(Xh, Wkh, bk, nullptr, Kt,
        T_TOK, DM, DM, DM, 0, 0, 0, 1.f, 0);
    gemm_nt<2><<<dim3(8, 128, 1), blk, 0, stream>>>(Xh, Wvh, bv, nullptr, Vt,
        T_TOK, DM, DM, DM, 0, 0, 0, 1.f, 0);

    // ---- ktv2[b][k][v] = NT(Kt[b], Vt[b]) * 0.125 -----------------------
    gemm_nt<1><<<dim3(8, 8, NB), blk, 0, stream>>>(Kt, Vt, nullptr, nullptr, ktv2,
        DM, DM, SEQ, SEQ, (long long)DM * SEQ, (long long)DM * SEQ, (long long)DM * DM,
        0.125f, 0);

    // ---- M2t[b][n][k] = NT(Wuh, ktv2[b]) --------------------------------
    gemm_nt<1><<<dim3(8, 8, NB), blk, 0, stream>>>(Wuh, ktv2, nullptr, nullptr, M2t,
        DM, DM, DM, DM, 0, (long long)DM * DM, (long long)DM * DM, 1.f, 0);

    // ---- usum = NT256(Q, M2t[b]) + bu + Xf  (fp32, residual fused) ------
    gemm256<0><<<dim3(4, 8, NB), blk5, 0, stream>>>(Qh, M2t, bu, Xf, usum,
        DM, DM, DM, (long long)SEQ * DM, (long long)DM * DM, (long long)SEQ * DM,
        0, 0, 0, 0, 1.f, 0);

    // ---- h1 = LN(usum): in-place fp32 + fp16 ----------------------------
    add_ln_kernel<<<T_TOK, blk, 0, stream>>>(usum, nullptr, nullptr, nullptr,
                                             g1, be1, h1f, h1h);

    // ---- FFN, 2 chunks of 8192 rows; FFN2 split-K=2, sum fused into LN --
    for (int c = 0; c < 2; c++) {
        const half_t* h1c = h1h + (long long)c * 8192 * DM;
        gemm256<1><<<dim3(16, 32, 1), blk5, 0, stream>>>(h1c, W1h, b1, nullptr, f1h,
            FFD, DM, DM, 0, 0, 0, 0, 0, 0, 0, 1.f, 1);
        // split-K=2: kz=0 -> Pff[0], kz=1 -> Pff[1]; b2 folded into LN below
        gemm256<0><<<dim3(4, 32, 2), blk5, 0, stream>>>(f1h, W2h, nullptr, nullptr, Pff,
            DM, 2048, FFD, 0, 0, 0,
            2048, 2048, (long long)8192 * DM, 1, 1.f, 0);
        add_ln_kernel<<<8192, blk, 0, stream>>>(h1f + (long long)c * 8192 * DM,
            Pff, Pff + (long long)8192 * DM, b2, g2, be2,
            nullptr, h2h + (long long)c * 8192 * DM);
    }

    // ---- head: l1 = relu(h2@W3+b3) fp16; LOG = l1@W4p + b4p (N=128) -----
    gemm_nt<1><<<dim3(4, 128, 1), blk, 0, stream>>>(h2h, W3h, b3, nullptr, l1h,
        T_TOK, 512, DM, DM, 0, 0, 0, 1.f, 1);
    gemm_nt<0><<<dim3(1, 128, 1), blk, 0, stream>>>(l1h, W4h, b4p, nullptr, LOG,
        T_TOK, 128, 512, 512, 0, 0, 0, 1.f, 0);

    // ---- out = sigmoid(LN75(logits)) ------------------------------------
    ln75_sigmoid_kernel<<<T_TOK, 64, 0, stream>>>(LOG, g3, be3, out);
}